// Round 1
// baseline (742.065 us; speedup 1.0000x reference)
//
#include <hip/hip_runtime.h>
#include <cstdint>

constexpr int IN_DIM = 128;
constexpr int OUT_DIM = 128;
constexpr int HEADS = 8;
constexpr float NEG_SLOPE = 0.2f;

// ---------------- K1: projection + per-node attention halves ----------------
// xp[N][128] = x[N][128] @ W[128][128]; als[N][8] = xp . a_src ; ald likewise.
// Block: 256 threads, 4x4 register tile each => 64 rows x 64 cols per block.
// blockIdx.y selects column half so static LDS stays at exactly 64 KB.
__global__ __launch_bounds__(256) void proj_kernel(
    const float* __restrict__ x, const float* __restrict__ W,
    const float* __restrict__ a_src, const float* __restrict__ a_dst,
    float* __restrict__ xp, float* __restrict__ als, float* __restrict__ ald,
    int N)
{
  __shared__ float Wl[128 * 64];   // [k][c] col-half of W
  __shared__ float xs[64 * 128];   // [row][k], 16B-granule xor-swizzled by (row>>2)&3
  const int t  = threadIdx.x;
  const int ch = blockIdx.y;
  const int r0 = blockIdx.x * 64;

  // stage W col-half (8192 floats), linear
  const float* wbase = W + ch * 64;
#pragma unroll
  for (int j = 0; j < 8; ++j) {
    int lidx = (t + j * 256) * 4;      // 0..8188 step 4
    int k = lidx >> 6;
    int c = lidx & 63;
    *(float4*)&Wl[lidx] = *(const float4*)&wbase[k * 128 + c];
  }
  // stage x tile, swizzling 16B granules: phys_c4 = c4 ^ ((row>>2)&3)
#pragma unroll
  for (int j = 0; j < 8; ++j) {
    int lidx = (t + j * 256) * 4;
    int row  = lidx >> 7;
    int colf = lidx & 127;
    int c4   = colf >> 2;
    int grow = r0 + row;
    float4 v = make_float4(0.f, 0.f, 0.f, 0.f);
    if (grow < N) v = *(const float4*)&x[(size_t)grow * IN_DIM + colf];
    int pc4 = c4 ^ ((row >> 2) & 3);
    *(float4*)&xs[row * 128 + (pc4 << 2)] = v;
  }
  __syncthreads();

  const int cg  = t & 15;   // col group: cols 4cg..4cg+3 (within half)
  const int rg  = t >> 4;   // row group: rows 4rg..4rg+3
  const int swz = rg & 3;

  float acc[4][4];
#pragma unroll
  for (int i = 0; i < 4; ++i)
#pragma unroll
    for (int j = 0; j < 4; ++j) acc[i][j] = 0.f;

#pragma unroll 2
  for (int kk = 0; kk < 32; ++kk) {
    float4 xv[4], wv[4];
#pragma unroll
    for (int i = 0; i < 4; ++i)
      xv[i] = *(const float4*)&xs[(4 * rg + i) * 128 + ((kk ^ swz) << 2)];
#pragma unroll
    for (int j = 0; j < 4; ++j)
      wv[j] = *(const float4*)&Wl[(4 * kk + j) * 64 + 4 * cg];
#pragma unroll
    for (int i = 0; i < 4; ++i) {
      const float* xi = (const float*)&xv[i];
#pragma unroll
      for (int j = 0; j < 4; ++j) {
        const float* wj = (const float*)&wv[j];
        float xk = xi[j];
#pragma unroll
        for (int c = 0; c < 4; ++c)
          acc[i][c] = fmaf(xk, wj[c], acc[i][c]);
      }
    }
  }

  // epilogue: write xp, reduce attention halves over the 4 threads of a head
  const int cbase = ch * 64 + 4 * cg;   // global col of acc[.][0]
  float asv[4], adv[4];
  *(float4*)asv = *(const float4*)&a_src[cbase];
  *(float4*)adv = *(const float4*)&a_dst[cbase];
#pragma unroll
  for (int r = 0; r < 4; ++r) {
    int grow = r0 + 4 * rg + r;
    float sp = acc[r][0]*asv[0] + acc[r][1]*asv[1] + acc[r][2]*asv[2] + acc[r][3]*asv[3];
    float dp = acc[r][0]*adv[0] + acc[r][1]*adv[1] + acc[r][2]*adv[2] + acc[r][3]*adv[3];
    sp += __shfl_xor(sp, 1); sp += __shfl_xor(sp, 2);
    dp += __shfl_xor(dp, 1); dp += __shfl_xor(dp, 2);
    if (grow < N) {
      float4 o;
      ((float*)&o)[0] = acc[r][0]; ((float*)&o)[1] = acc[r][1];
      ((float*)&o)[2] = acc[r][2]; ((float*)&o)[3] = acc[r][3];
      *(float4*)&xp[(size_t)grow * OUT_DIM + cbase] = o;
      if ((cg & 3) == 0) {
        int h = cbase >> 4;
        als[grow * HEADS + h] = sp;
        ald[grow * HEADS + h] = dp;
      }
    }
  }
}

// ---------------- dtype detection (JAX may downgrade int64 -> int32) --------
// Device-side only: no host sync allowed under graph capture.
__global__ void detect_kernel(const void* __restrict__ ei, int E, int N,
                              int* __restrict__ flag) {
  if (blockIdx.x == 0 && threadIdx.x == 0) {
    const long long* e64 = (const long long*)ei;
    int is64 = 1;
    int step = E > 64 ? E / 64 : 1;
    for (int i = 0; i < 64; ++i) {
      long long v = e64[(size_t)i * step % E];
      if (v < 0 || v >= (long long)N) { is64 = 0; break; }
    }
    *flag = is64;
  }
}

__device__ __forceinline__ int load_idx(const void* ei, size_t i, int is64) {
  return is64 ? (int)((const long long*)ei)[i] : ((const int*)ei)[i];
}

// ---------------- K2: degree histogram ----------------
__global__ void hist_kernel(const void* __restrict__ ei, int* __restrict__ deg,
                            int E, const int* __restrict__ flag) {
  const int is64 = *flag;
  int idx = blockIdx.x * blockDim.x + threadIdx.x;
  int stride = gridDim.x * blockDim.x;
  for (int e = idx; e < E; e += stride)
    atomicAdd(&deg[load_idx(ei, (size_t)E + e, is64)], 1);
}

// ---------------- K3: single-block exclusive scan ----------------
__global__ __launch_bounds__(1024) void scan_kernel(const int* __restrict__ deg,
    int* __restrict__ row_off, int* __restrict__ cursor, int N, int E) {
  __shared__ int lds[1024];
  const int t = threadIdx.x;
  const int chunk = (N + 1023) >> 10;
  const int lo = t * chunk;
  const int hi = min(lo + chunk, N);
  int s = 0;
  for (int i = lo; i < hi; ++i) s += deg[i];
  lds[t] = s;
  __syncthreads();
  for (int d = 1; d < 1024; d <<= 1) {
    int v = (t >= d) ? lds[t - d] : 0;
    __syncthreads();
    lds[t] += v;
    __syncthreads();
  }
  int run = (t == 0) ? 0 : lds[t - 1];
  for (int i = lo; i < hi; ++i) {
    row_off[i] = run;
    cursor[i]  = run;
    run += deg[i];
  }
  if (t == 0) row_off[N] = E;
}

// ---------------- K4: CSR scatter ----------------
__global__ void scatter_kernel(const void* __restrict__ ei, int* __restrict__ cursor,
                               int* __restrict__ csr, int E, const int* __restrict__ flag) {
  const int is64 = *flag;
  int idx = blockIdx.x * blockDim.x + threadIdx.x;
  int stride = gridDim.x * blockDim.x;
  for (int e = idx; e < E; e += stride) {
    int s = load_idx(ei, (size_t)e, is64);
    int d = load_idx(ei, (size_t)E + e, is64);
    int pos = atomicAdd(&cursor[d], 1);
    csr[pos] = s;
  }
}

// ---------------- K5: per-dst softmax + aggregation (1 wave / node) --------
// lane owns output cols {lane, lane+64}; per-head denom is accumulated
// redundantly in each of the 16 lanes of a head -> no reductions, no atomics.
__global__ __launch_bounds__(256) void aggregate_kernel(
    const float* __restrict__ xp, const float* __restrict__ als,
    const float* __restrict__ ald, const int* __restrict__ row_off,
    const int* __restrict__ csr, const float* __restrict__ bias,
    float* __restrict__ out, int N)
{
  int node = blockIdx.x * 4 + (threadIdx.x >> 6);
  if (node >= N) return;
  const int lane = threadIdx.x & 63;
  const int h0 = lane >> 4;                 // head of col lane  (0..3)
  const float ad0 = ald[node * HEADS + h0];
  const float ad1 = ald[node * HEADS + h0 + 4];
  const int beg = row_off[node], end = row_off[node + 1];
  float acc0 = 0.f, acc1 = 0.f, den0 = 0.f, den1 = 0.f;
  for (int i = beg; i < end; ++i) {
    int src = csr[i];
    const float* xr = xp + (size_t)src * OUT_DIM;
    float e0 = als[src * HEADS + h0] + ad0;
    float e1 = als[src * HEADS + h0 + 4] + ad1;
    e0 = e0 >= 0.f ? e0 : NEG_SLOPE * e0;
    e1 = e1 >= 0.f ? e1 : NEG_SLOPE * e1;
    float w0 = __expf(e0);
    float w1 = __expf(e1);
    den0 += w0; den1 += w1;
    acc0 = fmaf(w0, xr[lane], acc0);
    acc1 = fmaf(w1, xr[lane + 64], acc1);
  }
  float v0 = den0 > 0.f ? acc0 / den0 : 0.f;
  float v1 = den1 > 0.f ? acc1 / den1 : 0.f;
  v0 += bias[lane];
  v1 += bias[lane + 64];
  out[(size_t)node * OUT_DIM + lane]      = v0 > 0.f ? v0 : expm1f(v0);
  out[(size_t)node * OUT_DIM + lane + 64] = v1 > 0.f ? v1 : expm1f(v1);
}

// ---------------- launch ----------------
extern "C" void kernel_launch(void* const* d_in, const int* in_sizes, int n_in,
                              void* d_out, int out_size, void* d_ws, size_t ws_size,
                              hipStream_t stream) {
  const float* x      = (const float*)d_in[0];
  const void*  ei     = d_in[1];
  const float* W      = (const float*)d_in[2];
  const float* a_src  = (const float*)d_in[3];
  const float* a_dst  = (const float*)d_in[4];
  const float* bias   = (const float*)d_in[5];
  float* out = (float*)d_out;
  const int N = in_sizes[0] / IN_DIM;
  const int E = in_sizes[1] / 2;

  // workspace layout (all 16B-aligned); total ~65.3 MB
  char* ws = (char*)d_ws;
  size_t off = 0;
  float* xp      = (float*)(ws + off); off += (size_t)N * OUT_DIM * 4;
  float* als     = (float*)(ws + off); off += (size_t)N * HEADS * 4;
  float* ald     = (float*)(ws + off); off += (size_t)N * HEADS * 4;
  int*   deg     = (int*)(ws + off);   off += (size_t)N * 4;
  int*   row_off = (int*)(ws + off);   off += ((size_t)N + 4) * 4;
  int*   cursor  = (int*)(ws + off);   off += (size_t)N * 4;
  int*   csr     = (int*)(ws + off);   off += (size_t)E * 4;
  int*   flag    = (int*)(ws + off);   off += 16;

  hipMemsetAsync(deg, 0, (size_t)N * 4, stream);
  detect_kernel<<<1, 64, 0, stream>>>(ei, E, N, flag);

  dim3 pgrid((N + 63) / 64, 2);
  proj_kernel<<<pgrid, 256, 0, stream>>>(x, W, a_src, a_dst, xp, als, ald, N);

  hist_kernel<<<2048, 256, 0, stream>>>(ei, deg, E, flag);
  scan_kernel<<<1, 1024, 0, stream>>>(deg, row_off, cursor, N, E);
  scatter_kernel<<<2048, 256, 0, stream>>>(ei, cursor, csr, E, flag);
  aggregate_kernel<<<(N + 3) / 4, 256, 0, stream>>>(xp, als, ald, row_off, csr,
                                                    bias, out, N);
}

// Round 2
// 484.863 us; speedup vs baseline: 1.5305x; 1.5305x over previous
//
#include <hip/hip_runtime.h>
#include <cstdint>

constexpr int IN_DIM = 128;
constexpr int OUT_DIM = 128;
constexpr int HEADS = 8;
constexpr float NEG_SLOPE = 0.2f;

// ---------------- K1: projection + per-node attention halves ----------------
// xp[N][128] = x[N][128] @ W[128][128]; als[N][8] = xp . a_src ; ald likewise.
// Block: 256 threads, 4x4 register tile each => 64 rows x 64 cols per block.
// blockIdx.y selects column half so static LDS stays at exactly 64 KB.
__global__ __launch_bounds__(256) void proj_kernel(
    const float* __restrict__ x, const float* __restrict__ W,
    const float* __restrict__ a_src, const float* __restrict__ a_dst,
    float* __restrict__ xp, float* __restrict__ als, float* __restrict__ ald,
    int N)
{
  __shared__ float Wl[128 * 64];   // [k][c] col-half of W
  __shared__ float xs[64 * 128];   // [row][k], 16B-granule xor-swizzled by (row>>2)&3
  const int t  = threadIdx.x;
  const int ch = blockIdx.y;
  const int r0 = blockIdx.x * 64;

  // stage W col-half (8192 floats), linear
  const float* wbase = W + ch * 64;
#pragma unroll
  for (int j = 0; j < 8; ++j) {
    int lidx = (t + j * 256) * 4;      // 0..8188 step 4
    int k = lidx >> 6;
    int c = lidx & 63;
    *(float4*)&Wl[lidx] = *(const float4*)&wbase[k * 128 + c];
  }
  // stage x tile, swizzling 16B granules: phys_c4 = c4 ^ ((row>>2)&3)
#pragma unroll
  for (int j = 0; j < 8; ++j) {
    int lidx = (t + j * 256) * 4;
    int row  = lidx >> 7;
    int colf = lidx & 127;
    int c4   = colf >> 2;
    int grow = r0 + row;
    float4 v = make_float4(0.f, 0.f, 0.f, 0.f);
    if (grow < N) v = *(const float4*)&x[(size_t)grow * IN_DIM + colf];
    int pc4 = c4 ^ ((row >> 2) & 3);
    *(float4*)&xs[row * 128 + (pc4 << 2)] = v;
  }
  __syncthreads();

  const int cg  = t & 15;   // col group: cols 4cg..4cg+3 (within half)
  const int rg  = t >> 4;   // row group: rows 4rg..4rg+3
  const int swz = rg & 3;

  float acc[4][4];
#pragma unroll
  for (int i = 0; i < 4; ++i)
#pragma unroll
    for (int j = 0; j < 4; ++j) acc[i][j] = 0.f;

#pragma unroll 2
  for (int kk = 0; kk < 32; ++kk) {
    float4 xv[4], wv[4];
#pragma unroll
    for (int i = 0; i < 4; ++i)
      xv[i] = *(const float4*)&xs[(4 * rg + i) * 128 + ((kk ^ swz) << 2)];
#pragma unroll
    for (int j = 0; j < 4; ++j)
      wv[j] = *(const float4*)&Wl[(4 * kk + j) * 64 + 4 * cg];
#pragma unroll
    for (int i = 0; i < 4; ++i) {
      const float* xi = (const float*)&xv[i];
#pragma unroll
      for (int j = 0; j < 4; ++j) {
        const float* wj = (const float*)&wv[j];
        float xk = xi[j];
#pragma unroll
        for (int c = 0; c < 4; ++c)
          acc[i][c] = fmaf(xk, wj[c], acc[i][c]);
      }
    }
  }

  // epilogue: write xp, reduce attention halves over the 4 threads of a head
  const int cbase = ch * 64 + 4 * cg;   // global col of acc[.][0]
  float asv[4], adv[4];
  *(float4*)asv = *(const float4*)&a_src[cbase];
  *(float4*)adv = *(const float4*)&a_dst[cbase];
#pragma unroll
  for (int r = 0; r < 4; ++r) {
    int grow = r0 + 4 * rg + r;
    float sp = acc[r][0]*asv[0] + acc[r][1]*asv[1] + acc[r][2]*asv[2] + acc[r][3]*asv[3];
    float dp = acc[r][0]*adv[0] + acc[r][1]*adv[1] + acc[r][2]*adv[2] + acc[r][3]*adv[3];
    sp += __shfl_xor(sp, 1); sp += __shfl_xor(sp, 2);
    dp += __shfl_xor(dp, 1); dp += __shfl_xor(dp, 2);
    if (grow < N) {
      float4 o;
      ((float*)&o)[0] = acc[r][0]; ((float*)&o)[1] = acc[r][1];
      ((float*)&o)[2] = acc[r][2]; ((float*)&o)[3] = acc[r][3];
      *(float4*)&xp[(size_t)grow * OUT_DIM + cbase] = o;
      if ((cg & 3) == 0) {
        int h = cbase >> 4;
        als[grow * HEADS + h] = sp;
        ald[grow * HEADS + h] = dp;
      }
    }
  }
}

// ---------------- dtype detection (JAX may downgrade int64 -> int32) --------
// Parallel: 64 lanes sample one int64 each; one round of latency.
__global__ void detect_kernel(const void* __restrict__ ei, int E, int N,
                              int* __restrict__ flag) {
  const long long* e64 = (const long long*)ei;
  int lane = threadIdx.x;
  int step = E > 64 ? E / 64 : 1;
  size_t idx = ((size_t)lane * step) % (size_t)E;
  long long v = e64[idx];
  int bad = (v < 0 || v >= (long long)N) ? 1 : 0;
  unsigned long long m = __ballot(bad);
  if (lane == 0) *flag = (m == 0ull) ? 1 : 0;
}

__device__ __forceinline__ int load_idx(const void* ei, size_t i, int is64) {
  return is64 ? (int)((const long long*)ei)[i] : ((const int*)ei)[i];
}

// ---------------- K2: degree histogram ----------------
__global__ void hist_kernel(const void* __restrict__ ei, int* __restrict__ deg,
                            int E, const int* __restrict__ flag) {
  const int is64 = *flag;
  int idx = blockIdx.x * blockDim.x + threadIdx.x;
  int stride = gridDim.x * blockDim.x;
  for (int e = idx; e < E; e += stride)
    atomicAdd(&deg[load_idx(ei, (size_t)E + e, is64)], 1);
}

// ---------------- K3: hierarchical exclusive scan (3 small kernels) --------
// K3a: per-256-block partial sums
__global__ __launch_bounds__(256) void scan_partial(const int* __restrict__ deg,
                                                    int* __restrict__ bsum, int N) {
  int i = blockIdx.x * 256 + threadIdx.x;
  int v = (i < N) ? deg[i] : 0;
#pragma unroll
  for (int d = 1; d < 64; d <<= 1) v += __shfl_xor(v, d);
  __shared__ int wsum[4];
  if ((threadIdx.x & 63) == 0) wsum[threadIdx.x >> 6] = v;
  __syncthreads();
  if (threadIdx.x == 0)
    bsum[blockIdx.x] = wsum[0] + wsum[1] + wsum[2] + wsum[3];
}

// K3b: single-block exclusive scan of block sums (nb <= 1024; nb=391 here)
__global__ __launch_bounds__(1024) void scan_bsum(int* __restrict__ bsum, int nb) {
  __shared__ int lds[1024];
  int t = threadIdx.x;
  int v = (t < nb) ? bsum[t] : 0;
  lds[t] = v;
  __syncthreads();
  for (int d = 1; d < 1024; d <<= 1) {
    int u = (t >= d) ? lds[t - d] : 0;
    __syncthreads();
    lds[t] += u;
    __syncthreads();
  }
  if (t < nb) bsum[t] = (t == 0) ? 0 : lds[t - 1];
}

// K3c: block-local exclusive scan + block offset -> row_off, cursor
__global__ __launch_bounds__(256) void scan_final(const int* __restrict__ deg,
    const int* __restrict__ bsum, int* __restrict__ row_off,
    int* __restrict__ cursor, int N, int E) {
  int i = blockIdx.x * 256 + threadIdx.x;
  int v = (i < N) ? deg[i] : 0;
  __shared__ int lds[256];
  lds[threadIdx.x] = v;
  __syncthreads();
  for (int d = 1; d < 256; d <<= 1) {
    int u = (threadIdx.x >= d) ? lds[threadIdx.x - d] : 0;
    __syncthreads();
    lds[threadIdx.x] += u;
    __syncthreads();
  }
  int excl = bsum[blockIdx.x] + lds[threadIdx.x] - v;
  if (i < N) {
    row_off[i] = excl;
    cursor[i]  = excl;
    if (i == N - 1) row_off[N] = excl + v;   // == E
  }
}

// ---------------- K4: CSR scatter ----------------
__global__ void scatter_kernel(const void* __restrict__ ei, int* __restrict__ cursor,
                               int* __restrict__ csr, int E, const int* __restrict__ flag) {
  const int is64 = *flag;
  int idx = blockIdx.x * blockDim.x + threadIdx.x;
  int stride = gridDim.x * blockDim.x;
  for (int e = idx; e < E; e += stride) {
    int s = load_idx(ei, (size_t)e, is64);
    int d = load_idx(ei, (size_t)E + e, is64);
    int pos = atomicAdd(&cursor[d], 1);
    csr[pos] = s;
  }
}

// ---------------- K5: per-dst softmax + aggregation (1 wave / node) --------
// lane owns output cols {lane, lane+64}; per-head denom is accumulated
// redundantly in each of the 16 lanes of a head -> no reductions, no atomics.
// Edge loop unrolled x2 so two gather chains are in flight.
__global__ __launch_bounds__(256) void aggregate_kernel(
    const float* __restrict__ xp, const float* __restrict__ als,
    const float* __restrict__ ald, const int* __restrict__ row_off,
    const int* __restrict__ csr, const float* __restrict__ bias,
    float* __restrict__ out, int N)
{
  int node = blockIdx.x * 4 + (threadIdx.x >> 6);
  if (node >= N) return;
  const int lane = threadIdx.x & 63;
  const int h0 = lane >> 4;                 // head of col lane  (0..3)
  const float ad0 = ald[node * HEADS + h0];
  const float ad1 = ald[node * HEADS + h0 + 4];
  const int beg = row_off[node], end = row_off[node + 1];
  float acc0 = 0.f, acc1 = 0.f, den0 = 0.f, den1 = 0.f;
  int i = beg;
  for (; i + 1 < end; i += 2) {
    int s0 = csr[i], s1 = csr[i + 1];
    const float* x0 = xp + (size_t)s0 * OUT_DIM;
    const float* x1 = xp + (size_t)s1 * OUT_DIM;
    float as00 = als[s0 * HEADS + h0], as01 = als[s0 * HEADS + h0 + 4];
    float as10 = als[s1 * HEADS + h0], as11 = als[s1 * HEADS + h0 + 4];
    float xv00 = x0[lane], xv01 = x0[lane + 64];
    float xv10 = x1[lane], xv11 = x1[lane + 64];
    float e00 = as00 + ad0; e00 = e00 >= 0.f ? e00 : NEG_SLOPE * e00;
    float e01 = as01 + ad1; e01 = e01 >= 0.f ? e01 : NEG_SLOPE * e01;
    float e10 = as10 + ad0; e10 = e10 >= 0.f ? e10 : NEG_SLOPE * e10;
    float e11 = as11 + ad1; e11 = e11 >= 0.f ? e11 : NEG_SLOPE * e11;
    float w00 = __expf(e00), w01 = __expf(e01);
    float w10 = __expf(e10), w11 = __expf(e11);
    den0 += w00; den0 += w10;
    den1 += w01; den1 += w11;
    acc0 = fmaf(w00, xv00, acc0); acc0 = fmaf(w10, xv10, acc0);
    acc1 = fmaf(w01, xv01, acc1); acc1 = fmaf(w11, xv11, acc1);
  }
  if (i < end) {
    int src = csr[i];
    const float* xr = xp + (size_t)src * OUT_DIM;
    float e0 = als[src * HEADS + h0] + ad0;
    float e1 = als[src * HEADS + h0 + 4] + ad1;
    e0 = e0 >= 0.f ? e0 : NEG_SLOPE * e0;
    e1 = e1 >= 0.f ? e1 : NEG_SLOPE * e1;
    float w0 = __expf(e0);
    float w1 = __expf(e1);
    den0 += w0; den1 += w1;
    acc0 = fmaf(w0, xr[lane], acc0);
    acc1 = fmaf(w1, xr[lane + 64], acc1);
  }
  float v0 = den0 > 0.f ? acc0 / den0 : 0.f;
  float v1 = den1 > 0.f ? acc1 / den1 : 0.f;
  v0 += bias[lane];
  v1 += bias[lane + 64];
  out[(size_t)node * OUT_DIM + lane]      = v0 > 0.f ? v0 : expm1f(v0);
  out[(size_t)node * OUT_DIM + lane + 64] = v1 > 0.f ? v1 : expm1f(v1);
}

// ---------------- launch ----------------
extern "C" void kernel_launch(void* const* d_in, const int* in_sizes, int n_in,
                              void* d_out, int out_size, void* d_ws, size_t ws_size,
                              hipStream_t stream) {
  const float* x      = (const float*)d_in[0];
  const void*  ei     = d_in[1];
  const float* W      = (const float*)d_in[2];
  const float* a_src  = (const float*)d_in[3];
  const float* a_dst  = (const float*)d_in[4];
  const float* bias   = (const float*)d_in[5];
  float* out = (float*)d_out;
  const int N = in_sizes[0] / IN_DIM;
  const int E = in_sizes[1] / 2;
  const int nb = (N + 255) / 256;   // 391 for N=100000 (scan_bsum needs <=1024)

  // workspace layout (all 16B-aligned); total ~65.3 MB
  char* ws = (char*)d_ws;
  size_t off = 0;
  float* xp      = (float*)(ws + off); off += (size_t)N * OUT_DIM * 4;
  float* als     = (float*)(ws + off); off += (size_t)N * HEADS * 4;
  float* ald     = (float*)(ws + off); off += (size_t)N * HEADS * 4;
  int*   deg     = (int*)(ws + off);   off += (size_t)N * 4;
  int*   row_off = (int*)(ws + off);   off += ((size_t)N + 4) * 4;
  int*   cursor  = (int*)(ws + off);   off += (size_t)N * 4;
  int*   csr     = (int*)(ws + off);   off += (size_t)E * 4;
  int*   flag    = (int*)(ws + off);   off += 16;
  int*   bsum    = (int*)(ws + off);   off += (size_t)(nb + 4) * 4;

  hipMemsetAsync(deg, 0, (size_t)N * 4, stream);
  detect_kernel<<<1, 64, 0, stream>>>(ei, E, N, flag);

  dim3 pgrid((N + 63) / 64, 2);
  proj_kernel<<<pgrid, 256, 0, stream>>>(x, W, a_src, a_dst, xp, als, ald, N);

  hist_kernel<<<2048, 256, 0, stream>>>(ei, deg, E, flag);
  scan_partial<<<nb, 256, 0, stream>>>(deg, bsum, N);
  scan_bsum<<<1, 1024, 0, stream>>>(bsum, nb);
  scan_final<<<nb, 256, 0, stream>>>(deg, bsum, row_off, cursor, N, E);
  scatter_kernel<<<2048, 256, 0, stream>>>(ei, cursor, csr, E, flag);
  aggregate_kernel<<<(N + 3) / 4, 256, 0, stream>>>(xp, als, ald, row_off, csr,
                                                    bias, out, N);
}

// Round 4
// 456.180 us; speedup vs baseline: 1.6267x; 1.0629x over previous
//
#include <hip/hip_runtime.h>
#include <hip/hip_fp16.h>
#include <cstdint>

constexpr int IN_DIM = 128;
constexpr int OUT_DIM = 128;
constexpr int HEADS = 8;
constexpr float NEG_SLOPE = 0.2f;

// ---------------- K1: projection + per-node attention halves ----------------
// xp[N][128](fp16) = x[N][128] @ W[128][128]; als/ald[N][8] = xp . a_{src,dst}.
// Block: 256 threads, 4x4 register tile each => 64 rows x 64 cols per block.
// blockIdx.y selects column half so static LDS stays at exactly 64 KB.
__global__ __launch_bounds__(256) void proj_kernel(
    const float* __restrict__ x, const float* __restrict__ W,
    const float* __restrict__ a_src, const float* __restrict__ a_dst,
    __half* __restrict__ xp, float* __restrict__ als, float* __restrict__ ald,
    int N)
{
  __shared__ float Wl[128 * 64];   // [k][c] col-half of W
  __shared__ float xs[64 * 128];   // [row][k], 16B-granule xor-swizzled by (row>>2)&3
  const int t  = threadIdx.x;
  const int ch = blockIdx.y;
  const int r0 = blockIdx.x * 64;

  // stage W col-half (8192 floats), linear
  const float* wbase = W + ch * 64;
#pragma unroll
  for (int j = 0; j < 8; ++j) {
    int lidx = (t + j * 256) * 4;      // 0..8188 step 4
    int k = lidx >> 6;
    int c = lidx & 63;
    *(float4*)&Wl[lidx] = *(const float4*)&wbase[k * 128 + c];
  }
  // stage x tile, swizzling 16B granules: phys_c4 = c4 ^ ((row>>2)&3)
#pragma unroll
  for (int j = 0; j < 8; ++j) {
    int lidx = (t + j * 256) * 4;
    int row  = lidx >> 7;
    int colf = lidx & 127;
    int c4   = colf >> 2;
    int grow = r0 + row;
    float4 v = make_float4(0.f, 0.f, 0.f, 0.f);
    if (grow < N) v = *(const float4*)&x[(size_t)grow * IN_DIM + colf];
    int pc4 = c4 ^ ((row >> 2) & 3);
    *(float4*)&xs[row * 128 + (pc4 << 2)] = v;
  }
  __syncthreads();

  const int cg  = t & 15;   // col group: cols 4cg..4cg+3 (within half)
  const int rg  = t >> 4;   // row group: rows 4rg..4rg+3
  const int swz = rg & 3;

  float acc[4][4];
#pragma unroll
  for (int i = 0; i < 4; ++i)
#pragma unroll
    for (int j = 0; j < 4; ++j) acc[i][j] = 0.f;

#pragma unroll 2
  for (int kk = 0; kk < 32; ++kk) {
    float4 xv[4], wv[4];
#pragma unroll
    for (int i = 0; i < 4; ++i)
      xv[i] = *(const float4*)&xs[(4 * rg + i) * 128 + ((kk ^ swz) << 2)];
#pragma unroll
    for (int j = 0; j < 4; ++j)
      wv[j] = *(const float4*)&Wl[(4 * kk + j) * 64 + 4 * cg];
#pragma unroll
    for (int i = 0; i < 4; ++i) {
      const float* xi = (const float*)&xv[i];
#pragma unroll
      for (int j = 0; j < 4; ++j) {
        const float* wj = (const float*)&wv[j];
        float xk = xi[j];
#pragma unroll
        for (int c = 0; c < 4; ++c)
          acc[i][c] = fmaf(xk, wj[c], acc[i][c]);
      }
    }
  }

  // epilogue: write xp (fp16), reduce attention halves across the head's 4 threads
  const int cbase = ch * 64 + 4 * cg;   // global col of acc[.][0]
  float asv[4], adv[4];
  *(float4*)asv = *(const float4*)&a_src[cbase];
  *(float4*)adv = *(const float4*)&a_dst[cbase];
#pragma unroll
  for (int r = 0; r < 4; ++r) {
    int grow = r0 + 4 * rg + r;
    float sp = acc[r][0]*asv[0] + acc[r][1]*asv[1] + acc[r][2]*asv[2] + acc[r][3]*asv[3];
    float dp = acc[r][0]*adv[0] + acc[r][1]*adv[1] + acc[r][2]*adv[2] + acc[r][3]*adv[3];
    sp += __shfl_xor(sp, 1); sp += __shfl_xor(sp, 2);
    dp += __shfl_xor(dp, 1); dp += __shfl_xor(dp, 2);
    if (grow < N) {
      union { __half2 h2[2]; float2 f2; } u;
      u.h2[0] = __floats2half2_rn(acc[r][0], acc[r][1]);
      u.h2[1] = __floats2half2_rn(acc[r][2], acc[r][3]);
      *(float2*)&xp[(size_t)grow * OUT_DIM + cbase] = u.f2;
      if ((cg & 3) == 0) {
        int h = cbase >> 4;
        als[grow * HEADS + h] = sp;
        ald[grow * HEADS + h] = dp;
      }
    }
  }
}

// ---------------- dtype detection (JAX may downgrade int64 -> int32) --------
__global__ void detect_kernel(const void* __restrict__ ei, int E, int N,
                              int* __restrict__ flag) {
  const long long* e64 = (const long long*)ei;
  int lane = threadIdx.x;
  int step = E > 64 ? E / 64 : 1;
  size_t idx = ((size_t)lane * step) % (size_t)E;
  long long v = e64[idx];
  int bad = (v < 0 || v >= (long long)N) ? 1 : 0;
  unsigned long long m = __ballot(bad);
  if (lane == 0) *flag = (m == 0ull) ? 1 : 0;
}

__device__ __forceinline__ int load_idx(const void* ei, size_t i, int is64) {
  return is64 ? (int)((const long long*)ei)[i] : ((const int*)ei)[i];
}

// ---------------- K2: degree histogram ----------------
__global__ void hist_kernel(const void* __restrict__ ei, int* __restrict__ deg,
                            int E, const int* __restrict__ flag) {
  const int is64 = *flag;
  int idx = blockIdx.x * blockDim.x + threadIdx.x;
  int stride = gridDim.x * blockDim.x;
  for (int e = idx; e < E; e += stride)
    atomicAdd(&deg[load_idx(ei, (size_t)E + e, is64)], 1);
}

// ---------------- K3: hierarchical exclusive scan (3 small kernels) --------
__global__ __launch_bounds__(256) void scan_partial(const int* __restrict__ deg,
                                                    int* __restrict__ bsum, int N) {
  int i = blockIdx.x * 256 + threadIdx.x;
  int v = (i < N) ? deg[i] : 0;
#pragma unroll
  for (int d = 1; d < 64; d <<= 1) v += __shfl_xor(v, d);
  __shared__ int wsum[4];
  if ((threadIdx.x & 63) == 0) wsum[threadIdx.x >> 6] = v;
  __syncthreads();
  if (threadIdx.x == 0)
    bsum[blockIdx.x] = wsum[0] + wsum[1] + wsum[2] + wsum[3];
}

__global__ __launch_bounds__(1024) void scan_bsum(int* __restrict__ bsum, int nb) {
  __shared__ int lds[1024];
  int t = threadIdx.x;
  int v = (t < nb) ? bsum[t] : 0;
  lds[t] = v;
  __syncthreads();
  for (int d = 1; d < 1024; d <<= 1) {
    int u = (t >= d) ? lds[t - d] : 0;
    __syncthreads();
    lds[t] += u;
    __syncthreads();
  }
  if (t < nb) bsum[t] = (t == 0) ? 0 : lds[t - 1];
}

__global__ __launch_bounds__(256) void scan_final(const int* __restrict__ deg,
    const int* __restrict__ bsum, int* __restrict__ row_off,
    int* __restrict__ cursor, int N, int E) {
  int i = blockIdx.x * 256 + threadIdx.x;
  int v = (i < N) ? deg[i] : 0;
  __shared__ int lds[256];
  lds[threadIdx.x] = v;
  __syncthreads();
  for (int d = 1; d < 256; d <<= 1) {
    int u = (threadIdx.x >= d) ? lds[threadIdx.x - d] : 0;
    __syncthreads();
    lds[threadIdx.x] += u;
    __syncthreads();
  }
  int excl = bsum[blockIdx.x] + lds[threadIdx.x] - v;
  if (i < N) {
    row_off[i] = excl;
    cursor[i]  = excl;
    if (i == N - 1) row_off[N] = excl + v;   // == E
  }
}

// ---------------- K4: CSR scatter ----------------
__global__ void scatter_kernel(const void* __restrict__ ei, int* __restrict__ cursor,
                               int* __restrict__ csr, int E, const int* __restrict__ flag) {
  const int is64 = *flag;
  int idx = blockIdx.x * blockDim.x + threadIdx.x;
  int stride = gridDim.x * blockDim.x;
  for (int e = idx; e < E; e += stride) {
    int s = load_idx(ei, (size_t)e, is64);
    int d = load_idx(ei, (size_t)E + e, is64);
    int pos = atomicAdd(&cursor[d], 1);
    csr[pos] = s;
  }
}

// ---------------- K5: per-dst softmax + aggregation (1 wave / node) --------
// lane owns adjacent cols {2*lane, 2*lane+1} -> single head h=lane>>3:
// 1 als load, 1 exp, 1 denominator per edge; per-head denom redundantly
// accumulated in the head's 8 lanes -> no reductions, no atomics.
__global__ __launch_bounds__(256) void aggregate_kernel(
    const __half* __restrict__ xp, const float* __restrict__ als,
    const float* __restrict__ ald, const int* __restrict__ row_off,
    const int* __restrict__ csr, const float* __restrict__ bias,
    float* __restrict__ out, int N)
{
  int node = blockIdx.x * 4 + (threadIdx.x >> 6);
  if (node >= N) return;
  const int lane = threadIdx.x & 63;
  const int h = lane >> 3;                 // head of cols 2*lane, 2*lane+1
  const float ad = ald[node * HEADS + h];
  int beg = row_off[node], end = row_off[node + 1];
  beg = __builtin_amdgcn_readfirstlane(beg);   // wave-uniform -> scalar loop
  end = __builtin_amdgcn_readfirstlane(end);
  float acc0 = 0.f, acc1 = 0.f, den = 0.f;
  int i = beg;
  for (; i + 1 < end; i += 2) {
    int s0 = csr[i], s1 = csr[i + 1];
    float as0 = als[s0 * HEADS + h];
    float as1 = als[s1 * HEADS + h];
    __half2 xv0 = *(const __half2*)&xp[(size_t)s0 * OUT_DIM + 2 * lane];
    __half2 xv1 = *(const __half2*)&xp[(size_t)s1 * OUT_DIM + 2 * lane];
    float e0 = as0 + ad; e0 = e0 >= 0.f ? e0 : NEG_SLOPE * e0;
    float e1 = as1 + ad; e1 = e1 >= 0.f ? e1 : NEG_SLOPE * e1;
    float w0 = __expf(e0), w1 = __expf(e1);
    den += w0 + w1;
    float2 f0 = __half22float2(xv0), f1 = __half22float2(xv1);
    acc0 = fmaf(w0, f0.x, acc0); acc1 = fmaf(w0, f0.y, acc1);
    acc0 = fmaf(w1, f1.x, acc0); acc1 = fmaf(w1, f1.y, acc1);
  }
  if (i < end) {
    int s0 = csr[i];
    float as0 = als[s0 * HEADS + h];
    __half2 xv0 = *(const __half2*)&xp[(size_t)s0 * OUT_DIM + 2 * lane];
    float e0 = as0 + ad; e0 = e0 >= 0.f ? e0 : NEG_SLOPE * e0;
    float w0 = __expf(e0);
    den += w0;
    float2 f0 = __half22float2(xv0);
    acc0 = fmaf(w0, f0.x, acc0); acc1 = fmaf(w0, f0.y, acc1);
  }
  float inv = den > 0.f ? 1.f / den : 0.f;
  float2 b = *(const float2*)&bias[2 * lane];
  float v0 = fmaf(acc0, inv, b.x);
  float v1 = fmaf(acc1, inv, b.y);
  float2 o;
  o.x = v0 > 0.f ? v0 : expm1f(v0);
  o.y = v1 > 0.f ? v1 : expm1f(v1);
  *(float2*)&out[(size_t)node * OUT_DIM + 2 * lane] = o;
}

// ---------------- launch ----------------
extern "C" void kernel_launch(void* const* d_in, const int* in_sizes, int n_in,
                              void* d_out, int out_size, void* d_ws, size_t ws_size,
                              hipStream_t stream) {
  const float* x      = (const float*)d_in[0];
  const void*  ei     = d_in[1];
  const float* W      = (const float*)d_in[2];
  const float* a_src  = (const float*)d_in[3];
  const float* a_dst  = (const float*)d_in[4];
  const float* bias   = (const float*)d_in[5];
  float* out = (float*)d_out;
  const int N = in_sizes[0] / IN_DIM;
  const int E = in_sizes[1] / 2;
  const int nb = (N + 255) / 256;   // 391 for N=100000 (scan_bsum needs <=1024)

  // workspace layout (all 16B-aligned); total ~40 MB
  char* ws = (char*)d_ws;
  size_t off = 0;
  __half* xp     = (__half*)(ws + off); off += (size_t)N * OUT_DIM * 2;
  off = (off + 15) & ~(size_t)15;
  float* als     = (float*)(ws + off); off += (size_t)N * HEADS * 4;
  float* ald     = (float*)(ws + off); off += (size_t)N * HEADS * 4;
  int*   deg     = (int*)(ws + off);   off += (size_t)N * 4;
  int*   row_off = (int*)(ws + off);   off += ((size_t)N + 4) * 4;
  int*   cursor  = (int*)(ws + off);   off += (size_t)N * 4;
  int*   csr     = (int*)(ws + off);   off += (size_t)E * 4;
  int*   flag    = (int*)(ws + off);   off += 16;
  int*   bsum    = (int*)(ws + off);   off += (size_t)(nb + 4) * 4;

  hipMemsetAsync(deg, 0, (size_t)N * 4, stream);
  detect_kernel<<<1, 64, 0, stream>>>(ei, E, N, flag);

  dim3 pgrid((N + 63) / 64, 2);
  proj_kernel<<<pgrid, 256, 0, stream>>>(x, W, a_src, a_dst, xp, als, ald, N);

  hist_kernel<<<2048, 256, 0, stream>>>(ei, deg, E, flag);
  scan_partial<<<nb, 256, 0, stream>>>(deg, bsum, N);
  scan_bsum<<<1, 1024, 0, stream>>>(bsum, nb);
  scan_final<<<nb, 256, 0, stream>>>(deg, bsum, row_off, cursor, N, E);
  scatter_kernel<<<2048, 256, 0, stream>>>(ei, cursor, csr, E, flag);
  aggregate_kernel<<<(N + 3) / 4, 256, 0, stream>>>(xp, als, ald, row_off, csr,
                                                    bias, out, N);
}

// Round 5
// 286.555 us; speedup vs baseline: 2.5896x; 1.5919x over previous
//
#include <hip/hip_runtime.h>
#include <hip/hip_fp16.h>
#include <cstdint>

constexpr int IN_DIM = 128;
constexpr int OUT_DIM = 128;
constexpr int HEADS = 8;
constexpr float NEG_SLOPE = 0.2f;

// Bucket sort parameters: bucket = dst >> 8 (256 nodes per bucket).
// N = 100000 -> NB = 391 buckets, avg 4096 edges/bucket, sigma ~64.
constexpr int BUCKET_CAP = 5120;      // mean + 16 sigma; cannot overflow in practice
constexpr int BIN_TILE   = 4096;      // edges per bin_kernel block (16/thread)

// ---------------- K1: projection + per-node attention halves ----------------
// xp[N][128](fp16) = x[N][128] @ W[128][128]; als/ald[N][8] = xp . a_{src,dst}.
// 256 threads, 4x4 register tile => 64 rows x 64 cols per block; blockIdx.y
// selects column half so static LDS stays at 64 KB.
__global__ __launch_bounds__(256) void proj_kernel(
    const float* __restrict__ x, const float* __restrict__ W,
    const float* __restrict__ a_src, const float* __restrict__ a_dst,
    __half* __restrict__ xp, float* __restrict__ als, float* __restrict__ ald,
    int N)
{
  __shared__ float Wl[128 * 64];   // [k][c] col-half of W
  __shared__ float xs[64 * 128];   // [row][k], 16B-granule xor-swizzled by (row>>2)&3
  const int t  = threadIdx.x;
  const int ch = blockIdx.y;
  const int r0 = blockIdx.x * 64;

  const float* wbase = W + ch * 64;
#pragma unroll
  for (int j = 0; j < 8; ++j) {
    int lidx = (t + j * 256) * 4;      // 0..8188 step 4
    int k = lidx >> 6;
    int c = lidx & 63;
    *(float4*)&Wl[lidx] = *(const float4*)&wbase[k * 128 + c];
  }
#pragma unroll
  for (int j = 0; j < 8; ++j) {
    int lidx = (t + j * 256) * 4;
    int row  = lidx >> 7;
    int colf = lidx & 127;
    int c4   = colf >> 2;
    int grow = r0 + row;
    float4 v = make_float4(0.f, 0.f, 0.f, 0.f);
    if (grow < N) v = *(const float4*)&x[(size_t)grow * IN_DIM + colf];
    int pc4 = c4 ^ ((row >> 2) & 3);
    *(float4*)&xs[row * 128 + (pc4 << 2)] = v;
  }
  __syncthreads();

  const int cg  = t & 15;
  const int rg  = t >> 4;
  const int swz = rg & 3;

  float acc[4][4];
#pragma unroll
  for (int i = 0; i < 4; ++i)
#pragma unroll
    for (int j = 0; j < 4; ++j) acc[i][j] = 0.f;

#pragma unroll 2
  for (int kk = 0; kk < 32; ++kk) {
    float4 xv[4], wv[4];
#pragma unroll
    for (int i = 0; i < 4; ++i)
      xv[i] = *(const float4*)&xs[(4 * rg + i) * 128 + ((kk ^ swz) << 2)];
#pragma unroll
    for (int j = 0; j < 4; ++j)
      wv[j] = *(const float4*)&Wl[(4 * kk + j) * 64 + 4 * cg];
#pragma unroll
    for (int i = 0; i < 4; ++i) {
      const float* xi = (const float*)&xv[i];
#pragma unroll
      for (int j = 0; j < 4; ++j) {
        const float* wj = (const float*)&wv[j];
        float xk = xi[j];
#pragma unroll
        for (int c = 0; c < 4; ++c)
          acc[i][c] = fmaf(xk, wj[c], acc[i][c]);
      }
    }
  }

  const int cbase = ch * 64 + 4 * cg;
  float asv[4], adv[4];
  *(float4*)asv = *(const float4*)&a_src[cbase];
  *(float4*)adv = *(const float4*)&a_dst[cbase];
#pragma unroll
  for (int r = 0; r < 4; ++r) {
    int grow = r0 + 4 * rg + r;
    float sp = acc[r][0]*asv[0] + acc[r][1]*asv[1] + acc[r][2]*asv[2] + acc[r][3]*asv[3];
    float dp = acc[r][0]*adv[0] + acc[r][1]*adv[1] + acc[r][2]*adv[2] + acc[r][3]*adv[3];
    sp += __shfl_xor(sp, 1); sp += __shfl_xor(sp, 2);
    dp += __shfl_xor(dp, 1); dp += __shfl_xor(dp, 2);
    if (grow < N) {
      union { __half2 h2[2]; float2 f2; } u;
      u.h2[0] = __floats2half2_rn(acc[r][0], acc[r][1]);
      u.h2[1] = __floats2half2_rn(acc[r][2], acc[r][3]);
      *(float2*)&xp[(size_t)grow * OUT_DIM + cbase] = u.f2;
      if ((cg & 3) == 0) {
        int h = cbase >> 4;
        als[grow * HEADS + h] = sp;
        ald[grow * HEADS + h] = dp;
      }
    }
  }
}

// ---------------- dtype detection (JAX may downgrade int64 -> int32) --------
__global__ void detect_kernel(const void* __restrict__ ei, int E, int N,
                              int* __restrict__ flag) {
  const long long* e64 = (const long long*)ei;
  int lane = threadIdx.x;
  int step = E > 64 ? E / 64 : 1;
  size_t idx = ((size_t)lane * step) % (size_t)E;
  long long v = e64[idx];
  int bad = (v < 0 || v >= (long long)N) ? 1 : 0;
  unsigned long long m = __ballot(bad);
  if (lane == 0) *flag = (m == 0ull) ? 1 : 0;
}

__device__ __forceinline__ int load_idx(const void* ei, size_t i, int is64) {
  return is64 ? (int)((const long long*)ei)[i] : ((const int*)ei)[i];
}

// ---------------- K2: bin edges into 256-node-wide dst buckets --------------
// One block = BIN_TILE edges. LDS histogram over buckets, ONE global atomic
// per (block, bucket) to reserve a private chunk, then place 4B records
// ((dst&255)<<24 | src) into the chunk. 153K atomics total vs 3.2M before.
__global__ __launch_bounds__(256) void bin_kernel(
    const void* __restrict__ ei, const int* __restrict__ flag,
    int* __restrict__ bucket_cnt, unsigned int* __restrict__ buckets,
    int E)
{
  __shared__ int cnt[512];          // per-bucket count, then chunk cursor
  const int is64 = *flag;
  const int t = threadIdx.x;
  cnt[t] = 0; cnt[t + 256] = 0;
  __syncthreads();

  unsigned int rec[16];
  short bk[16];
  const int base_e = blockIdx.x * BIN_TILE;
#pragma unroll
  for (int j = 0; j < 16; ++j) {
    int idx = base_e + j * 256 + t;
    bk[j] = -1;
    if (idx < E) {
      int s = load_idx(ei, (size_t)idx, is64);
      int d = load_idx(ei, (size_t)E + idx, is64);
      rec[j] = ((unsigned)(d & 255) << 24) | (unsigned)s;
      bk[j] = (short)(d >> 8);
      atomicAdd(&cnt[d >> 8], 1);
    }
  }
  __syncthreads();

  // reserve global chunks; cnt[b] becomes this block's cursor into bucket b
  int c0 = cnt[t];
  cnt[t] = (c0 > 0) ? atomicAdd(&bucket_cnt[t], c0) : 0;
  int c1 = cnt[t + 256];
  cnt[t + 256] = (c1 > 0) ? atomicAdd(&bucket_cnt[t + 256], c1) : 0;
  __syncthreads();

#pragma unroll
  for (int j = 0; j < 16; ++j) {
    if (bk[j] >= 0) {
      int pos = atomicAdd(&cnt[bk[j]], 1);
      if (pos < BUCKET_CAP)
        buckets[(size_t)bk[j] * BUCKET_CAP + pos] = rec[j];
    }
  }
}

// ---------------- K3: exclusive scan of 512 bucket counts -------------------
__global__ __launch_bounds__(512) void bucket_scan(const int* __restrict__ bucket_cnt,
                                                   int* __restrict__ bucket_base) {
  __shared__ int lds[512];
  int t = threadIdx.x;
  int v = bucket_cnt[t];
  lds[t] = v;
  __syncthreads();
  for (int d = 1; d < 512; d <<= 1) {
    int u = (t >= d) ? lds[t - d] : 0;
    __syncthreads();
    lds[t] += u;
    __syncthreads();
  }
  bucket_base[t] = lds[t] - v;        // exclusive
  if (t == 511) bucket_base[512] = lds[511];
}

// ---------------- K4: per-bucket LDS counting sort -> csr + row_off ---------
// One block per bucket: sort <=BUCKET_CAP records by dst&255 (256 bins).
// Bin prefix sums ARE the row offsets for the bucket's 256 nodes.
__global__ __launch_bounds__(256) void sort_bucket(
    const unsigned int* __restrict__ buckets, const int* __restrict__ bucket_base,
    int* __restrict__ csr, int* __restrict__ row_off, int N, int E)
{
  __shared__ unsigned int recs[BUCKET_CAP];   // 20 KB
  __shared__ int cnt[256];
  __shared__ int sc[256];
  const int b = blockIdx.x;
  const int t = threadIdx.x;
  const int base = bucket_base[b];
  int m = bucket_base[b + 1] - base;
  if (m > BUCKET_CAP) m = BUCKET_CAP;

  cnt[t] = 0;
  __syncthreads();
  for (int i = t; i < m; i += 256) {
    unsigned int r = buckets[(size_t)b * BUCKET_CAP + i];
    recs[i] = r;
    atomicAdd(&cnt[r >> 24], 1);
  }
  __syncthreads();

  // exclusive scan of cnt over 256 bins
  sc[t] = cnt[t];
  __syncthreads();
  for (int d = 1; d < 256; d <<= 1) {
    int u = (t >= d) ? sc[t - d] : 0;
    __syncthreads();
    sc[t] += u;
    __syncthreads();
  }
  int excl = sc[t] - cnt[t];

  // row_off for node (b<<8)+t comes free
  int n = (b << 8) + t;
  if (n < N) row_off[n] = base + excl;
  if (b == 0 && t == 0) row_off[N] = E;

  cnt[t] = base + excl;   // global cursor per bin
  __syncthreads();
  for (int i = t; i < m; i += 256) {
    unsigned int r = recs[i];
    int pos = atomicAdd(&cnt[r >> 24], 1);   // LDS atomic
    csr[pos] = (int)(r & 0x00FFFFFFu);
  }
}

// ---------------- K5: per-dst softmax + aggregation (1 wave / node) --------
// lane owns adjacent cols {2*lane, 2*lane+1} -> single head h=lane>>3:
// 1 als load, 1 exp, 1 denominator per edge; no reductions, no atomics.
__global__ __launch_bounds__(256) void aggregate_kernel(
    const __half* __restrict__ xp, const float* __restrict__ als,
    const float* __restrict__ ald, const int* __restrict__ row_off,
    const int* __restrict__ csr, const float* __restrict__ bias,
    float* __restrict__ out, int N)
{
  int node = blockIdx.x * 4 + (threadIdx.x >> 6);
  if (node >= N) return;
  const int lane = threadIdx.x & 63;
  const int h = lane >> 3;
  const float ad = ald[node * HEADS + h];
  int beg = row_off[node], end = row_off[node + 1];
  beg = __builtin_amdgcn_readfirstlane(beg);
  end = __builtin_amdgcn_readfirstlane(end);
  float acc0 = 0.f, acc1 = 0.f, den = 0.f;
  int i = beg;
  for (; i + 1 < end; i += 2) {
    int s0 = csr[i], s1 = csr[i + 1];
    float as0 = als[s0 * HEADS + h];
    float as1 = als[s1 * HEADS + h];
    __half2 xv0 = *(const __half2*)&xp[(size_t)s0 * OUT_DIM + 2 * lane];
    __half2 xv1 = *(const __half2*)&xp[(size_t)s1 * OUT_DIM + 2 * lane];
    float e0 = as0 + ad; e0 = e0 >= 0.f ? e0 : NEG_SLOPE * e0;
    float e1 = as1 + ad; e1 = e1 >= 0.f ? e1 : NEG_SLOPE * e1;
    float w0 = __expf(e0), w1 = __expf(e1);
    den += w0 + w1;
    float2 f0 = __half22float2(xv0), f1 = __half22float2(xv1);
    acc0 = fmaf(w0, f0.x, acc0); acc1 = fmaf(w0, f0.y, acc1);
    acc0 = fmaf(w1, f1.x, acc0); acc1 = fmaf(w1, f1.y, acc1);
  }
  if (i < end) {
    int s0 = csr[i];
    float as0 = als[s0 * HEADS + h];
    __half2 xv0 = *(const __half2*)&xp[(size_t)s0 * OUT_DIM + 2 * lane];
    float e0 = as0 + ad; e0 = e0 >= 0.f ? e0 : NEG_SLOPE * e0;
    float w0 = __expf(e0);
    den += w0;
    float2 f0 = __half22float2(xv0);
    acc0 = fmaf(w0, f0.x, acc0); acc1 = fmaf(w0, f0.y, acc1);
  }
  float inv = den > 0.f ? 1.f / den : 0.f;
  float2 b = *(const float2*)&bias[2 * lane];
  float v0 = fmaf(acc0, inv, b.x);
  float v1 = fmaf(acc1, inv, b.y);
  float2 o;
  o.x = v0 > 0.f ? v0 : expm1f(v0);
  o.y = v1 > 0.f ? v1 : expm1f(v1);
  *(float2*)&out[(size_t)node * OUT_DIM + 2 * lane] = o;
}

// ---------------- launch ----------------
extern "C" void kernel_launch(void* const* d_in, const int* in_sizes, int n_in,
                              void* d_out, int out_size, void* d_ws, size_t ws_size,
                              hipStream_t stream) {
  const float* x      = (const float*)d_in[0];
  const void*  ei     = d_in[1];
  const float* W      = (const float*)d_in[2];
  const float* a_src  = (const float*)d_in[3];
  const float* a_dst  = (const float*)d_in[4];
  const float* bias   = (const float*)d_in[5];
  float* out = (float*)d_out;
  const int N = in_sizes[0] / IN_DIM;
  const int E = in_sizes[1] / 2;
  const int NB  = (N + 255) >> 8;            // buckets (<=512)
  const int nbt = (E + BIN_TILE - 1) / BIN_TILE;

  // workspace layout (16B-aligned); total ~46 MB
  char* ws = (char*)d_ws;
  size_t off = 0;
  __half* xp          = (__half*)(ws + off); off += (size_t)N * OUT_DIM * 2;
  off = (off + 15) & ~(size_t)15;
  float* als          = (float*)(ws + off);  off += (size_t)N * HEADS * 4;
  float* ald          = (float*)(ws + off);  off += (size_t)N * HEADS * 4;
  int*   bucket_cnt   = (int*)(ws + off);    off += 512 * 4;
  int*   bucket_base  = (int*)(ws + off);    off += 516 * 4;
  unsigned int* buckets = (unsigned int*)(ws + off); off += (size_t)512 * BUCKET_CAP * 4;
  int*   csr          = (int*)(ws + off);    off += (size_t)E * 4;
  int*   row_off      = (int*)(ws + off);    off += ((size_t)N + 4) * 4;
  int*   flag         = (int*)(ws + off);    off += 16;

  hipMemsetAsync(bucket_cnt, 0, 512 * 4, stream);
  detect_kernel<<<1, 64, 0, stream>>>(ei, E, N, flag);

  dim3 pgrid((N + 63) / 64, 2);
  proj_kernel<<<pgrid, 256, 0, stream>>>(x, W, a_src, a_dst, xp, als, ald, N);

  bin_kernel<<<nbt, 256, 0, stream>>>(ei, flag, bucket_cnt, buckets, E);
  bucket_scan<<<1, 512, 0, stream>>>(bucket_cnt, bucket_base);
  sort_bucket<<<NB, 256, 0, stream>>>(buckets, bucket_base, csr, row_off, N, E);
  aggregate_kernel<<<(N + 3) / 4, 256, 0, stream>>>(xp, als, ald, row_off, csr,
                                                    bias, out, N);
}

// Round 6
// 256.937 us; speedup vs baseline: 2.8881x; 1.1153x over previous
//
#include <hip/hip_runtime.h>
#include <hip/hip_fp16.h>
#include <cstdint>

constexpr int IN_DIM = 128;
constexpr int OUT_DIM = 128;
constexpr int HEADS = 8;
constexpr float NEG_SLOPE = 0.2f;

constexpr int BUCKET_CAP = 5120;
constexpr int BIN_TILE   = 4096;

typedef _Float16 f16x8 __attribute__((ext_vector_type(8)));
typedef float    f32x4 __attribute__((ext_vector_type(4)));

// ---------------- K1: projection via MFMA fp16 ----------------
// xp[N][128](fp16) = x[N][128] @ W[128][128], fp32 accumulate.
// Block: 256 thr = 4 waves; tile 64 rows x 128 cols. LDS: x-tile fp16 (16KB,
// XOR-swizzled 16B granules by row&15) + W^T fp16 (32KB, swizzled by col&15).
// Fragments (m92-verified layout): A lane row=l&15, k=8*(l>>4)+i;
// B(=W^T) lane col=l&15, same k; C col=l&15, row=4*(l>>4)+reg.
__global__ __launch_bounds__(256) void proj_kernel(
    const float* __restrict__ x, const float* __restrict__ W,
    __half* __restrict__ xp, int N)
{
  __shared__ __half xs[64 * 128];    // 16 KB, reused as output bounce
  __shared__ __half Wt[128 * 128];   // 32 KB, [col][k]
  const int t  = threadIdx.x;
  const int r0 = blockIdx.x * 64;

  // stage x tile -> fp16, swizzled: granule g=k>>3, phys g^(row&15)
#pragma unroll
  for (int it = 0; it < 4; ++it) {
    int m   = t + it * 256;          // 1024 granule tasks
    int row = m >> 4;
    int g   = m & 15;
    int grow = r0 + row;
    float4 v0 = make_float4(0.f,0.f,0.f,0.f), v1 = v0;
    if (grow < N) {
      const float* src = &x[(size_t)grow * IN_DIM + g * 8];
      v0 = *(const float4*)src;
      v1 = *(const float4*)(src + 4);
    }
    union { __half2 h2[4]; uint4 u; } u;
    u.h2[0] = __floats2half2_rn(v0.x, v0.y);
    u.h2[1] = __floats2half2_rn(v0.z, v0.w);
    u.h2[2] = __floats2half2_rn(v1.x, v1.y);
    u.h2[3] = __floats2half2_rn(v1.z, v1.w);
    *(uint4*)&xs[row * 128 + ((g ^ (row & 15)) << 3)] = u.u;
  }
  // stage W^T -> fp16 [col][k], swizzled by col&15
#pragma unroll
  for (int it = 0; it < 16; ++it) {
    int m  = t + it * 256;           // 4096 tasks: (col, k-quad)
    int c  = m & 127;
    int kq = m >> 7;                 // 0..31
    int k  = kq * 4;
    float w0 = W[(size_t)(k + 0) * OUT_DIM + c];
    float w1 = W[(size_t)(k + 1) * OUT_DIM + c];
    float w2 = W[(size_t)(k + 2) * OUT_DIM + c];
    float w3 = W[(size_t)(k + 3) * OUT_DIM + c];
    union { __half2 h2[2]; uint2 u; } u;
    u.h2[0] = __floats2half2_rn(w0, w1);
    u.h2[1] = __floats2half2_rn(w2, w3);
    int g = k >> 3;
    *(uint2*)&Wt[c * 128 + (((g ^ (c & 15)) << 3) + (k & 7))] = u.u;
  }
  __syncthreads();

  const int wv = t >> 6;       // wave -> rows 16*wv .. +15
  const int l  = t & 63;
  const int fr = l & 15;
  const int fq = l >> 4;

  f32x4 acc[8];
#pragma unroll
  for (int ct = 0; ct < 8; ++ct) acc[ct] = (f32x4){0.f,0.f,0.f,0.f};

#pragma unroll
  for (int ks = 0; ks < 4; ++ks) {
    int g = 4 * ks + fq;
    f16x8 a = *(const f16x8*)&xs[(16 * wv + fr) * 128 + ((g ^ fr) << 3)];
#pragma unroll
    for (int ct = 0; ct < 8; ++ct) {
      f16x8 b = *(const f16x8*)&Wt[(16 * ct + fr) * 128 + ((g ^ fr) << 3)];
      acc[ct] = __builtin_amdgcn_mfma_f32_16x16x32_f16(a, b, acc[ct], 0, 0, 0);
    }
  }
  __syncthreads();   // all MFMA reads of xs done; reuse as output bounce

  // scatter acc -> xs[row][col] fp16
#pragma unroll
  for (int ct = 0; ct < 8; ++ct)
#pragma unroll
    for (int r = 0; r < 4; ++r)
      xs[(16 * wv + 4 * fq + r) * 128 + 16 * ct + fr] = __float2half(acc[ct][r]);
  __syncthreads();

  // coalesced write-back: 1024 uint4 tasks
#pragma unroll
  for (int it = 0; it < 4; ++it) {
    int m   = t + it * 256;
    int row = m >> 4;
    int u4  = m & 15;
    int grow = r0 + row;
    if (grow < N) {
      uint4 v = *(const uint4*)&xs[row * 128 + u4 * 8];
      *(uint4*)&xp[(size_t)grow * OUT_DIM + u4 * 8] = v;
    }
  }
}

// ---------------- K1b: per-node attention halves from xp ----------------
// wave per node: lane owns cols {2l,2l+1} (head l>>3); 8-lane head reduce.
__global__ __launch_bounds__(256) void att_kernel(
    const __half* __restrict__ xp, const float* __restrict__ a_src,
    const float* __restrict__ a_dst, float* __restrict__ als,
    float* __restrict__ ald, int N)
{
  int node = blockIdx.x * 4 + (threadIdx.x >> 6);
  if (node >= N) return;
  const int l = threadIdx.x & 63;
  float2 f  = __half22float2(*(const __half2*)&xp[(size_t)node * OUT_DIM + 2 * l]);
  float2 as = *(const float2*)&a_src[2 * l];
  float2 ad = *(const float2*)&a_dst[2 * l];
  float sp = f.x * as.x + f.y * as.y;
  float dp = f.x * ad.x + f.y * ad.y;
  sp += __shfl_xor(sp, 1); sp += __shfl_xor(sp, 2); sp += __shfl_xor(sp, 4);
  dp += __shfl_xor(dp, 1); dp += __shfl_xor(dp, 2); dp += __shfl_xor(dp, 4);
  if ((l & 7) == 0) {
    als[node * HEADS + (l >> 3)] = sp;
    ald[node * HEADS + (l >> 3)] = dp;
  }
}

// ---------------- dtype detection (JAX may downgrade int64 -> int32) --------
__global__ void detect_kernel(const void* __restrict__ ei, int E, int N,
                              int* __restrict__ flag) {
  const long long* e64 = (const long long*)ei;
  int lane = threadIdx.x;
  int step = E > 64 ? E / 64 : 1;
  size_t idx = ((size_t)lane * step) % (size_t)E;
  long long v = e64[idx];
  int bad = (v < 0 || v >= (long long)N) ? 1 : 0;
  unsigned long long m = __ballot(bad);
  if (lane == 0) *flag = (m == 0ull) ? 1 : 0;
}

__device__ __forceinline__ int load_idx(const void* ei, size_t i, int is64) {
  return is64 ? (int)((const long long*)ei)[i] : ((const int*)ei)[i];
}

// ---------------- K2: bin edges into 256-node-wide dst buckets --------------
__global__ __launch_bounds__(256) void bin_kernel(
    const void* __restrict__ ei, const int* __restrict__ flag,
    int* __restrict__ bucket_cnt, unsigned int* __restrict__ buckets,
    int E)
{
  __shared__ int cnt[512];
  const int is64 = *flag;
  const int t = threadIdx.x;
  cnt[t] = 0; cnt[t + 256] = 0;
  __syncthreads();

  unsigned int rec[16];
  short bk[16];
  const int base_e = blockIdx.x * BIN_TILE;
#pragma unroll
  for (int j = 0; j < 16; ++j) {
    int idx = base_e + j * 256 + t;
    bk[j] = -1;
    if (idx < E) {
      int s = load_idx(ei, (size_t)idx, is64);
      int d = load_idx(ei, (size_t)E + idx, is64);
      rec[j] = ((unsigned)(d & 255) << 24) | (unsigned)s;
      bk[j] = (short)(d >> 8);
      atomicAdd(&cnt[d >> 8], 1);
    }
  }
  __syncthreads();

  int c0 = cnt[t];
  cnt[t] = (c0 > 0) ? atomicAdd(&bucket_cnt[t], c0) : 0;
  int c1 = cnt[t + 256];
  cnt[t + 256] = (c1 > 0) ? atomicAdd(&bucket_cnt[t + 256], c1) : 0;
  __syncthreads();

#pragma unroll
  for (int j = 0; j < 16; ++j) {
    if (bk[j] >= 0) {
      int pos = atomicAdd(&cnt[bk[j]], 1);
      if (pos < BUCKET_CAP)
        buckets[(size_t)bk[j] * BUCKET_CAP + pos] = rec[j];
    }
  }
}

// ---------------- K3: exclusive scan of 512 bucket counts -------------------
__global__ __launch_bounds__(512) void bucket_scan(const int* __restrict__ bucket_cnt,
                                                   int* __restrict__ bucket_base) {
  __shared__ int lds[512];
  int t = threadIdx.x;
  int v = bucket_cnt[t];
  lds[t] = v;
  __syncthreads();
  for (int d = 1; d < 512; d <<= 1) {
    int u = (t >= d) ? lds[t - d] : 0;
    __syncthreads();
    lds[t] += u;
    __syncthreads();
  }
  bucket_base[t] = lds[t] - v;
  if (t == 511) bucket_base[512] = lds[511];
}

// ---------------- K4: per-bucket LDS counting sort -> csr + row_off ---------
__global__ __launch_bounds__(256) void sort_bucket(
    const unsigned int* __restrict__ buckets, const int* __restrict__ bucket_base,
    int* __restrict__ csr, int* __restrict__ row_off, int N, int E)
{
  __shared__ unsigned int recs[BUCKET_CAP];
  __shared__ int cnt[256];
  __shared__ int sc[256];
  const int b = blockIdx.x;
  const int t = threadIdx.x;
  const int base = bucket_base[b];
  int m = bucket_base[b + 1] - base;
  if (m > BUCKET_CAP) m = BUCKET_CAP;

  cnt[t] = 0;
  __syncthreads();
  for (int i = t; i < m; i += 256) {
    unsigned int r = buckets[(size_t)b * BUCKET_CAP + i];
    recs[i] = r;
    atomicAdd(&cnt[r >> 24], 1);
  }
  __syncthreads();

  sc[t] = cnt[t];
  __syncthreads();
  for (int d = 1; d < 256; d <<= 1) {
    int u = (t >= d) ? sc[t - d] : 0;
    __syncthreads();
    sc[t] += u;
    __syncthreads();
  }
  int excl = sc[t] - cnt[t];

  int n = (b << 8) + t;
  if (n < N) row_off[n] = base + excl;
  if (b == 0 && t == 0) row_off[N] = E;

  cnt[t] = base + excl;
  __syncthreads();
  for (int i = t; i < m; i += 256) {
    unsigned int r = recs[i];
    int pos = atomicAdd(&cnt[r >> 24], 1);
    csr[pos] = (int)(r & 0x00FFFFFFu);
  }
}

// ---------------- K5: softmax + aggregation, cooperative weights ------------
// Chunks of 8 edges: lane (j=l&7, h=l>>3) computes w(edge j, head h) ONCE
// (64 lanes = 8 edges x 8 heads, zero redundancy), broadcast via shfl.
// FMA phase: lane owns cols {2l,2l+1} of head l>>3. Per-head denom =
// shfl_xor reduce over j at the end. No atomics, no cross-head traffic.
__global__ __launch_bounds__(256) void aggregate_kernel(
    const __half* __restrict__ xp, const float* __restrict__ als,
    const float* __restrict__ ald, const int* __restrict__ row_off,
    const int* __restrict__ csr, const float* __restrict__ bias,
    float* __restrict__ out, int N)
{
  int node = blockIdx.x * 4 + (threadIdx.x >> 6);
  if (node >= N) return;
  const int lane = threadIdx.x & 63;
  const int j = lane & 7;          // edge slot (weight phase)
  const int h = lane >> 3;         // head (both phases)
  const float ad = ald[node * HEADS + h];
  int beg = row_off[node], end = row_off[node + 1];
  beg = __builtin_amdgcn_readfirstlane(beg);
  end = __builtin_amdgcn_readfirstlane(end);

  float acc0 = 0.f, acc1 = 0.f, den_p = 0.f;
  const int nfull = (end - beg) & ~7;
  const int full_end = beg + nfull;
  int i = beg;
  for (; i < full_end; i += 8) {
    int s = csr[i + j];
    float as = als[s * HEADS + h];
    float e = as + ad; e = e >= 0.f ? e : NEG_SLOPE * e;
    float w = __expf(e);
    den_p += w;
#pragma unroll
    for (int q = 0; q < 8; ++q) {
      int   sq = __shfl(s, q);                    // lane q holds edge q
      float wq = __shfl(w, (lane & 56) | q);      // lane h*8+q: (edge q, head h)
      float2 f = __half22float2(*(const __half2*)&xp[(size_t)sq * OUT_DIM + 2 * lane]);
      acc0 = fmaf(wq, f.x, acc0);
      acc1 = fmaf(wq, f.y, acc1);
    }
  }
  if (i < end) {
    int rem = end - i;               // 1..7, wave-uniform
    int idx = i + j;
    int s = csr[idx < end ? idx : i];
    float as = als[s * HEADS + h];
    float e = as + ad; e = e >= 0.f ? e : NEG_SLOPE * e;
    float w = (j < rem) ? __expf(e) : 0.f;
    den_p += w;
    for (int q = 0; q < rem; ++q) {
      int   sq = __shfl(s, q);
      float wq = __shfl(w, (lane & 56) | q);
      float2 f = __half22float2(*(const __half2*)&xp[(size_t)sq * OUT_DIM + 2 * lane]);
      acc0 = fmaf(wq, f.x, acc0);
      acc1 = fmaf(wq, f.y, acc1);
    }
  }
  // den for head h: sum partials over the 8 edge-slots (xor 1,2,4)
  den_p += __shfl_xor(den_p, 1);
  den_p += __shfl_xor(den_p, 2);
  den_p += __shfl_xor(den_p, 4);

  float inv = den_p > 0.f ? 1.f / den_p : 0.f;
  float2 b = *(const float2*)&bias[2 * lane];
  float v0 = fmaf(acc0, inv, b.x);
  float v1 = fmaf(acc1, inv, b.y);
  float2 o;
  o.x = v0 > 0.f ? v0 : expm1f(v0);
  o.y = v1 > 0.f ? v1 : expm1f(v1);
  *(float2*)&out[(size_t)node * OUT_DIM + 2 * lane] = o;
}

// ---------------- launch ----------------
extern "C" void kernel_launch(void* const* d_in, const int* in_sizes, int n_in,
                              void* d_out, int out_size, void* d_ws, size_t ws_size,
                              hipStream_t stream) {
  const float* x      = (const float*)d_in[0];
  const void*  ei     = d_in[1];
  const float* W      = (const float*)d_in[2];
  const float* a_src  = (const float*)d_in[3];
  const float* a_dst  = (const float*)d_in[4];
  const float* bias   = (const float*)d_in[5];
  float* out = (float*)d_out;
  const int N = in_sizes[0] / IN_DIM;
  const int E = in_sizes[1] / 2;
  const int NB  = (N + 255) >> 8;
  const int nbt = (E + BIN_TILE - 1) / BIN_TILE;

  char* ws = (char*)d_ws;
  size_t off = 0;
  __half* xp          = (__half*)(ws + off); off += (size_t)N * OUT_DIM * 2;
  off = (off + 15) & ~(size_t)15;
  float* als          = (float*)(ws + off);  off += (size_t)N * HEADS * 4;
  float* ald          = (float*)(ws + off);  off += (size_t)N * HEADS * 4;
  int*   bucket_cnt   = (int*)(ws + off);    off += 512 * 4;
  int*   bucket_base  = (int*)(ws + off);    off += 516 * 4;
  unsigned int* buckets = (unsigned int*)(ws + off); off += (size_t)512 * BUCKET_CAP * 4;
  int*   csr          = (int*)(ws + off);    off += (size_t)E * 4;
  int*   row_off      = (int*)(ws + off);    off += ((size_t)N + 4) * 4;
  int*   flag         = (int*)(ws + off);    off += 16;

  hipMemsetAsync(bucket_cnt, 0, 512 * 4, stream);
  detect_kernel<<<1, 64, 0, stream>>>(ei, E, N, flag);

  proj_kernel<<<(N + 63) / 64, 256, 0, stream>>>(x, W, xp, N);
  att_kernel<<<(N + 3) / 4, 256, 0, stream>>>(xp, a_src, a_dst, als, ald, N);

  bin_kernel<<<nbt, 256, 0, stream>>>(ei, flag, bucket_cnt, buckets, E);
  bucket_scan<<<1, 512, 0, stream>>>(bucket_cnt, bucket_base);
  sort_bucket<<<NB, 256, 0, stream>>>(buckets, bucket_base, csr, row_off, N, E);
  aggregate_kernel<<<(N + 3) / 4, 256, 0, stream>>>(xp, als, ald, row_off, csr,
                                                    bias, out, N);
}